// Round 1
// baseline (248.135 us; speedup 1.0000x reference)
//
#include <hip/hip_runtime.h>
#include <stdint.h>

#define LOG2E       1.4426950408889634f
#define INV_SQRT32  0.17677669529663687f

using bf16x8 = __attribute__((ext_vector_type(8))) short;
using f32x4  = __attribute__((ext_vector_type(4))) float;

__device__ __forceinline__ unsigned short f2bf(float f) {
  union { float f; uint32_t u; } v; v.f = f;
  uint32_t r = v.u + 0x7fffu + ((v.u >> 16) & 1u);   // RNE
  return (unsigned short)(r >> 16);
}
__device__ __forceinline__ float bflo(uint32_t u) { return __uint_as_float(u << 16); }
__device__ __forceinline__ float bfhi(uint32_t u) { return __uint_as_float(u & 0xffff0000u); }

typedef const __attribute__((address_space(1))) void* gas_ptr;
typedef __attribute__((address_space(3))) void*       las_ptr;
__device__ __forceinline__ void load_lds16(const void* g, void* l) {
  // wave-uniform LDS base; HW scatters lane i -> base + i*16
  __builtin_amdgcn_global_load_lds((gas_ptr)g, (las_ptr)l, 16, 0, 0);
}

// ---------- kernel 1: W (fp32) -> Wcat bf16 [768][256]; bias -> bias_cat fp32 [768]
__global__ __launch_bounds__(256) void convert_w(
    const float* __restrict__ wq, const float* __restrict__ bq,
    const float* __restrict__ wk, const float* __restrict__ bk,
    const float* __restrict__ wv, const float* __restrict__ bv,
    unsigned short* __restrict__ Wcat, float* __restrict__ biasc) {
  int idx = (blockIdx.x * 256 + threadIdx.x) * 4;   // flat into 768*256
  int p = idx >> 16;                                // which projection
  int rem = idx & 0xffff;
  const float* src = (p == 0) ? wq : (p == 1) ? wk : wv;
  float4 v = *(const float4*)(src + rem);
  ushort4 o;
  o.x = f2bf(v.x); o.y = f2bf(v.y); o.z = f2bf(v.z); o.w = f2bf(v.w);
  *(ushort4*)(Wcat + idx) = o;
  if (blockIdx.x < 3) {
    const float* sb = (blockIdx.x == 0) ? bq : (blockIdx.x == 1) ? bk : bv;
    biasc[blockIdx.x * 256 + threadIdx.x] = sb[threadIdx.x];
  }
}

// ---------- kernel 2: x fp32 [b][c][s] -> Xt bf16 [b][s][c]
__global__ __launch_bounds__(256) void transpose_x(const float* __restrict__ x,
                                                   unsigned short* __restrict__ xt) {
  __shared__ float tile[64 * 65];
  int b = blockIdx.z;
  int s0 = blockIdx.x * 64, c0 = blockIdx.y * 64;
  int t = threadIdx.x;
  int sl = t & 63, g = t >> 6;
  const float* xp = x + ((size_t)(b * 256 + c0)) * 4096 + s0 + sl;
#pragma unroll
  for (int ii = 0; ii < 16; ++ii) {
    int cl = g * 16 + ii;
    tile[cl * 65 + sl] = xp[(size_t)cl * 4096];
  }
  __syncthreads();
#pragma unroll
  for (int jj = 0; jj < 16; ++jj) {
    int s_loc = g * 16 + jj;
    float v = tile[sl * 65 + s_loc];
    xt[((size_t)(b * 4096 + s0 + s_loc)) * 256 + c0 + sl] = f2bf(v);
  }
}

// ---------- kernel 3: qkv[b][768][4096] bf16 = Wcat[768][256] * Xt[b][4096][256]^T + bias
// m97-style: 128x128 tile, BK=32, global_load_lds width-16, mfma 16x16x32 bf16
__global__ __launch_bounds__(256) void gemm_qkv(
    const unsigned short* __restrict__ Wc, const float* __restrict__ biasc,
    const unsigned short* __restrict__ Xt, unsigned short* __restrict__ qkv) {
  __shared__ unsigned short As[128 * 32];
  __shared__ unsigned short Bs[128 * 32];
  int blk = blockIdx.x;
  int b = blk / 192;
  int rest = blk - b * 192;
  int mt = rest >> 5, nt = rest & 31;
  int m0 = mt * 128, n0 = nt * 128;
  int tid = threadIdx.x;
  int lane = tid & 63, wave = tid >> 6;
  int quad = lane >> 4, rt = lane & 15;
  int wm = wave >> 1, wn = wave & 1;

  f32x4 acc[4][4];
#pragma unroll
  for (int i = 0; i < 4; ++i)
#pragma unroll
    for (int j = 0; j < 4; ++j) acc[i][j] = (f32x4){0.f, 0.f, 0.f, 0.f};

  int lr = lane >> 2;          // row within 16-row wave chunk
  int lk = (lane & 3) * 8;     // k element offset (8 bf16 = 16 B)
  const unsigned short* gA0 = Wc + (size_t)(m0 + (wave * 2 + 0) * 16 + lr) * 256 + lk;
  const unsigned short* gA1 = Wc + (size_t)(m0 + (wave * 2 + 1) * 16 + lr) * 256 + lk;
  const unsigned short* gB0 = Xt + ((size_t)b * 4096 + n0 + (wave * 2 + 0) * 16 + lr) * 256 + lk;
  const unsigned short* gB1 = Xt + ((size_t)b * 4096 + n0 + (wave * 2 + 1) * 16 + lr) * 256 + lk;
  unsigned short* lA0 = &As[(wave * 2 + 0) * 16 * 32];
  unsigned short* lA1 = &As[(wave * 2 + 1) * 16 * 32];
  unsigned short* lB0 = &Bs[(wave * 2 + 0) * 16 * 32];
  unsigned short* lB1 = &Bs[(wave * 2 + 1) * 16 * 32];

#pragma unroll
  for (int kc = 0; kc < 8; ++kc) {
    int ko = kc * 32;
    load_lds16(gA0 + ko, lA0);
    load_lds16(gA1 + ko, lA1);
    load_lds16(gB0 + ko, lB0);
    load_lds16(gB1 + ko, lB1);
    __syncthreads();
    bf16x8 af[4], bfr[4];
#pragma unroll
    for (int mi = 0; mi < 4; ++mi)
      af[mi] = *(const bf16x8*)&As[(wm * 64 + mi * 16 + rt) * 32 + quad * 8];
#pragma unroll
    for (int ni = 0; ni < 4; ++ni)
      bfr[ni] = *(const bf16x8*)&Bs[(wn * 64 + ni * 16 + rt) * 32 + quad * 8];
#pragma unroll
    for (int mi = 0; mi < 4; ++mi)
#pragma unroll
      for (int ni = 0; ni < 4; ++ni)
        acc[mi][ni] = __builtin_amdgcn_mfma_f32_16x16x32_bf16(af[mi], bfr[ni], acc[mi][ni], 0, 0, 0);
    __syncthreads();
  }

  size_t obase = (size_t)b * 768;
#pragma unroll
  for (int mi = 0; mi < 4; ++mi) {
    int o = m0 + wm * 64 + mi * 16 + quad * 4;   // + r; C/D row = quad*4 + reg
    float bsv[4];
#pragma unroll
    for (int r = 0; r < 4; ++r) bsv[r] = biasc[o + r];
#pragma unroll
    for (int ni = 0; ni < 4; ++ni) {
      int s = n0 + wn * 64 + ni * 16 + rt;       // C/D col = lane&15
#pragma unroll
      for (int r = 0; r < 4; ++r)
        qkv[(obase + o + r) * 4096 + s] = f2bf(acc[mi][ni][r] + bsv[r]);
    }
  }
}

// ---------- kernel 4: per-(b, n, d) 64x64 attention over H, contraction over W
#define AST 68   // padded LDS row stride (floats): odd-in-16B -> conflict-free float4 rows
__global__ __launch_bounds__(256) void attn(const unsigned short* __restrict__ qkv,
                                            float* __restrict__ out) {
  __shared__ float QT[64 * AST];   // QT[w][h]
  __shared__ float KT[64 * AST];   // KT[w][g]
  __shared__ float Vf[64 * AST];   // Vf[g][w]
  __shared__ float Pf[64 * AST];   // scores then probabilities [h][g]
  __shared__ float red[4 * 64];
  __shared__ float rowmax[64];
  __shared__ float rowinv[64];
  int blk = blockIdx.x;
  int b = blk >> 8, o = blk & 255;   // o = n*32+d (flat)
  int t = threadIdx.x;
  size_t base = ((size_t)b * 768 + o) * 4096;
  const uint32_t* qrow = (const uint32_t*)(qkv + base) + t * 8;                 // 16 bf16/thread
  const uint32_t* krow = (const uint32_t*)(qkv + base + (size_t)256 * 4096) + t * 8;
  const uint32_t* vrow = (const uint32_t*)(qkv + base + (size_t)512 * 4096) + t * 8;
  int h = t >> 2, w0 = (t & 3) * 16;
#pragma unroll
  for (int c = 0; c < 2; ++c) {
    uint4 qd = *(const uint4*)(qrow + c * 4);
    uint4 kd = *(const uint4*)(krow + c * 4);
    uint4 vd = *(const uint4*)(vrow + c * 4);
    uint32_t qs[4] = {qd.x, qd.y, qd.z, qd.w};
    uint32_t ks[4] = {kd.x, kd.y, kd.z, kd.w};
    uint32_t vs[4] = {vd.x, vd.y, vd.z, vd.w};
#pragma unroll
    for (int e = 0; e < 4; ++e) {
      int w = w0 + c * 8 + e * 2;
      QT[(w + 0) * AST + h] = bflo(qs[e]);
      QT[(w + 1) * AST + h] = bfhi(qs[e]);
      KT[(w + 0) * AST + h] = bflo(ks[e]);
      KT[(w + 1) * AST + h] = bfhi(ks[e]);
      Vf[h * AST + w + 0] = bflo(vs[e]);
      Vf[h * AST + w + 1] = bfhi(vs[e]);
    }
  }
  __syncthreads();

  // S[h][g] = sum_w q[h][w] k[g][w] * 1/sqrt(32); 4x4 register tile per thread
  int th = (t >> 4) * 4;
  int tg = (t & 15) * 4;
  float sa[4][4] = {};
#pragma unroll 4
  for (int kk = 0; kk < 64; ++kk) {
    float4 qv = *(const float4*)&QT[kk * AST + th];
    float4 kv = *(const float4*)&KT[kk * AST + tg];
    float q[4] = {qv.x, qv.y, qv.z, qv.w};
    float k[4] = {kv.x, kv.y, kv.z, kv.w};
#pragma unroll
    for (int i = 0; i < 4; ++i)
#pragma unroll
      for (int j = 0; j < 4; ++j) sa[i][j] += q[i] * k[j];
  }
#pragma unroll
  for (int i = 0; i < 4; ++i) {
    float4 sv = {sa[i][0] * INV_SQRT32, sa[i][1] * INV_SQRT32,
                 sa[i][2] * INV_SQRT32, sa[i][3] * INV_SQRT32};
    *(float4*)&Pf[(th + i) * AST + tg] = sv;
  }
  __syncthreads();

  // softmax over g (row direction), 4 threads per row
  int hr = t & 63, qt = t >> 6;
  float m = -1e30f;
#pragma unroll
  for (int e = 0; e < 16; ++e) m = fmaxf(m, Pf[hr * AST + qt * 16 + e]);
  red[qt * 64 + hr] = m;
  __syncthreads();
  if (t < 64)
    rowmax[t] = fmaxf(fmaxf(red[t], red[64 + t]), fmaxf(red[128 + t], red[192 + t]));
  __syncthreads();
  float mrow = rowmax[hr];
  float ssum = 0.f;
#pragma unroll
  for (int e = 0; e < 16; ++e) {
    int idx = hr * AST + qt * 16 + e;
    float p = exp2f((Pf[idx] - mrow) * LOG2E);
    Pf[idx] = p;
    ssum += p;
  }
  red[qt * 64 + hr] = ssum;
  __syncthreads();
  if (t < 64) rowinv[t] = 1.f / (red[t] + red[64 + t] + red[128 + t] + red[192 + t]);
  __syncthreads();

  // ctx[h][w] = (sum_g P[h][g] V[g][w]) * rowinv[h]; 4x4 register tile
  float ca[4][4] = {};
#pragma unroll 4
  for (int g = 0; g < 64; ++g) {
    float4 vv = *(const float4*)&Vf[g * AST + tg];
    float v[4] = {vv.x, vv.y, vv.z, vv.w};
    float p0 = Pf[(th + 0) * AST + g];
    float p1 = Pf[(th + 1) * AST + g];
    float p2 = Pf[(th + 2) * AST + g];
    float p3 = Pf[(th + 3) * AST + g];
#pragma unroll
    for (int j = 0; j < 4; ++j) {
      ca[0][j] += p0 * v[j];
      ca[1][j] += p1 * v[j];
      ca[2][j] += p2 * v[j];
      ca[3][j] += p3 * v[j];
    }
  }
  float* op = out + ((size_t)(b * 256 + o)) * 4096;
#pragma unroll
  for (int i = 0; i < 4; ++i) {
    float inv = rowinv[th + i];
    float4 r = {ca[i][0] * inv, ca[i][1] * inv, ca[i][2] * inv, ca[i][3] * inv};
    *(float4*)(op + (th + i) * 64 + tg) = r;
  }
}

extern "C" void kernel_launch(void* const* d_in, const int* in_sizes, int n_in,
                              void* d_out, int out_size, void* d_ws, size_t ws_size,
                              hipStream_t stream) {
  const float* x  = (const float*)d_in[0];
  const float* wq = (const float*)d_in[1];
  const float* bq = (const float*)d_in[2];
  const float* wk = (const float*)d_in[3];
  const float* bk = (const float*)d_in[4];
  const float* wv = (const float*)d_in[5];
  const float* bv = (const float*)d_in[6];
  float* out = (float*)d_out;

  // workspace layout (bytes): Wcat bf16 393216 | bias fp32 3072 | Xt bf16 33554432 | qkv bf16 100663296
  char* ws = (char*)d_ws;
  unsigned short* Wcat  = (unsigned short*)ws;
  float*          biasc = (float*)(ws + 393216);
  unsigned short* Xt    = (unsigned short*)(ws + 396288);
  unsigned short* qkv   = (unsigned short*)(ws + 396288 + 33554432);

  hipLaunchKernelGGL(convert_w, dim3(192), dim3(256), 0, stream,
                     wq, bq, wk, bk, wv, bv, Wcat, biasc);
  hipLaunchKernelGGL(transpose_x, dim3(64, 4, 16), dim3(256), 0, stream, x, Xt);
  hipLaunchKernelGGL(gemm_qkv, dim3(3072), dim3(256), 0, stream, Wcat, biasc, Xt, qkv);
  hipLaunchKernelGGL(attn, dim3(4096), dim3(256), 0, stream, qkv, out);
}

// Round 2
// 199.393 us; speedup vs baseline: 1.2445x; 1.2445x over previous
//
#include <hip/hip_runtime.h>
#include <stdint.h>

#define LOG2E       1.4426950408889634f
#define INV_SQRT32  0.17677669529663687f

using bf16x8 = __attribute__((ext_vector_type(8))) short;
using f32x4  = __attribute__((ext_vector_type(4))) float;

__device__ __forceinline__ unsigned short f2bf(float f) {
  union { float f; uint32_t u; } v; v.f = f;
  uint32_t r = v.u + 0x7fffu + ((v.u >> 16) & 1u);   // RNE
  return (unsigned short)(r >> 16);
}

typedef const __attribute__((address_space(1))) void* gas_ptr;
typedef __attribute__((address_space(3))) void*       las_ptr;
__device__ __forceinline__ void load_lds16(const void* g, void* l) {
  // wave-uniform LDS base; HW scatters lane i -> base + i*16
  __builtin_amdgcn_global_load_lds((gas_ptr)g, (las_ptr)l, 16, 0, 0);
}

// ---------- kernel 1: W (fp32) -> Wcat bf16 [768][256]; bias -> bias_cat fp32 [768]
__global__ __launch_bounds__(256) void convert_w(
    const float* __restrict__ wq, const float* __restrict__ bq,
    const float* __restrict__ wk, const float* __restrict__ bk,
    const float* __restrict__ wv, const float* __restrict__ bv,
    unsigned short* __restrict__ Wcat, float* __restrict__ biasc) {
  int idx = (blockIdx.x * 256 + threadIdx.x) * 4;   // flat into 768*256
  int p = idx >> 16;                                // which projection
  int rem = idx & 0xffff;
  const float* src = (p == 0) ? wq : (p == 1) ? wk : wv;
  float4 v = *(const float4*)(src + rem);
  ushort4 o;
  o.x = f2bf(v.x); o.y = f2bf(v.y); o.z = f2bf(v.z); o.w = f2bf(v.w);
  *(ushort4*)(Wcat + idx) = o;
  if (blockIdx.x < 3) {
    const float* sb = (blockIdx.x == 0) ? bq : (blockIdx.x == 1) ? bk : bv;
    biasc[blockIdx.x * 256 + threadIdx.x] = sb[threadIdx.x];
  }
}

// ---------- kernel 2: x fp32 [b][c][s] -> Xt bf16 [b][s][c]
__global__ __launch_bounds__(256) void transpose_x(const float* __restrict__ x,
                                                   unsigned short* __restrict__ xt) {
  __shared__ float tile[64 * 65];
  int b = blockIdx.z;
  int s0 = blockIdx.x * 64, c0 = blockIdx.y * 64;
  int t = threadIdx.x;
  int sl = t & 63, g = t >> 6;
  const float* xp = x + ((size_t)(b * 256 + c0)) * 4096 + s0 + sl;
#pragma unroll
  for (int ii = 0; ii < 16; ++ii) {
    int cl = g * 16 + ii;
    tile[cl * 65 + sl] = xp[(size_t)cl * 4096];
  }
  __syncthreads();
#pragma unroll
  for (int jj = 0; jj < 16; ++jj) {
    int s_loc = g * 16 + jj;
    float v = tile[sl * 65 + s_loc];
    xt[((size_t)(b * 4096 + s0 + s_loc)) * 256 + c0 + sl] = f2bf(v);
  }
}

// ---------- kernel 3: qkv[b][768][4096] bf16 = Wcat[768][256] * Xt[b][4096][256]^T + bias
__global__ __launch_bounds__(256) void gemm_qkv(
    const unsigned short* __restrict__ Wc, const float* __restrict__ biasc,
    const unsigned short* __restrict__ Xt, unsigned short* __restrict__ qkv) {
  __shared__ unsigned short As[128 * 32];
  __shared__ unsigned short Bs[128 * 32];
  int blk = blockIdx.x;
  int b = blk / 192;
  int rest = blk - b * 192;
  int mt = rest >> 5, nt = rest & 31;
  int m0 = mt * 128, n0 = nt * 128;
  int tid = threadIdx.x;
  int lane = tid & 63, wave = tid >> 6;
  int quad = lane >> 4, rt = lane & 15;
  int wm = wave >> 1, wn = wave & 1;

  f32x4 acc[4][4];
#pragma unroll
  for (int i = 0; i < 4; ++i)
#pragma unroll
    for (int j = 0; j < 4; ++j) acc[i][j] = (f32x4){0.f, 0.f, 0.f, 0.f};

  int lr = lane >> 2;          // row within 16-row wave chunk
  int lk = (lane & 3) * 8;     // k element offset (8 bf16 = 16 B)
  const unsigned short* gA0 = Wc + (size_t)(m0 + (wave * 2 + 0) * 16 + lr) * 256 + lk;
  const unsigned short* gA1 = Wc + (size_t)(m0 + (wave * 2 + 1) * 16 + lr) * 256 + lk;
  const unsigned short* gB0 = Xt + ((size_t)b * 4096 + n0 + (wave * 2 + 0) * 16 + lr) * 256 + lk;
  const unsigned short* gB1 = Xt + ((size_t)b * 4096 + n0 + (wave * 2 + 1) * 16 + lr) * 256 + lk;
  unsigned short* lA0 = &As[(wave * 2 + 0) * 16 * 32];
  unsigned short* lA1 = &As[(wave * 2 + 1) * 16 * 32];
  unsigned short* lB0 = &Bs[(wave * 2 + 0) * 16 * 32];
  unsigned short* lB1 = &Bs[(wave * 2 + 1) * 16 * 32];

#pragma unroll
  for (int kc = 0; kc < 8; ++kc) {
    int ko = kc * 32;
    load_lds16(gA0 + ko, lA0);
    load_lds16(gA1 + ko, lA1);
    load_lds16(gB0 + ko, lB0);
    load_lds16(gB1 + ko, lB1);
    __syncthreads();
    bf16x8 af[4], bfr[4];
#pragma unroll
    for (int mi = 0; mi < 4; ++mi)
      af[mi] = *(const bf16x8*)&As[(wm * 64 + mi * 16 + rt) * 32 + quad * 8];
#pragma unroll
    for (int ni = 0; ni < 4; ++ni)
      bfr[ni] = *(const bf16x8*)&Bs[(wn * 64 + ni * 16 + rt) * 32 + quad * 8];
#pragma unroll
    for (int mi = 0; mi < 4; ++mi)
#pragma unroll
      for (int ni = 0; ni < 4; ++ni)
        acc[mi][ni] = __builtin_amdgcn_mfma_f32_16x16x32_bf16(af[mi], bfr[ni], acc[mi][ni], 0, 0, 0);
    __syncthreads();
  }

  size_t obase = (size_t)b * 768;
#pragma unroll
  for (int mi = 0; mi < 4; ++mi) {
    int o = m0 + wm * 64 + mi * 16 + quad * 4;   // + r; C/D row = quad*4 + reg
    float bsv[4];
#pragma unroll
    for (int r = 0; r < 4; ++r) bsv[r] = biasc[o + r];
#pragma unroll
    for (int ni = 0; ni < 4; ++ni) {
      int s = n0 + wn * 64 + ni * 16 + rt;       // C/D col = lane&15
#pragma unroll
      for (int r = 0; r < 4; ++r)
        qkv[(obase + o + r) * 4096 + s] = f2bf(acc[mi][ni][r] + bsv[r]);
    }
  }
}

// ---------- kernel 4: per-(b, o) 64x64 attention, MFMA-based
// S = Q K^T (contract w), softmax over g, O = P V (contract g)
// LDS layout (36608 B total, phase-overlaid):
//   phase1: Qs[64][72]bf16 @0 (9216), Ks[64][72]bf16 @9216 (9216)
//   phase2: Sf[64][65]f32  @0 (16640), Ps[64][72]bf16 @16640 (9216)
//   Vt[64][72]bf16 @25856 (9216) | red[4][64]f32 @35072 | rowmax @36096 | rowinv @36352
__global__ __launch_bounds__(256) void attn(const unsigned short* __restrict__ qkv,
                                            float* __restrict__ out) {
  __shared__ char sh[36608];
  unsigned short* Qs = (unsigned short*)sh;
  unsigned short* Ks = (unsigned short*)(sh + 9216);
  float*          Sf = (float*)sh;
  unsigned short* Ps = (unsigned short*)(sh + 16640);
  unsigned short* Vt = (unsigned short*)(sh + 25856);
  float* red    = (float*)(sh + 35072);
  float* rowmax = (float*)(sh + 36096);
  float* rowinv = (float*)(sh + 36352);

  int blk = blockIdx.x;
  int b = blk >> 8, o = blk & 255;
  int t = threadIdx.x;
  size_t base = ((size_t)b * 768 + o) * 4096;
  const unsigned short* qg = qkv + base;
  const unsigned short* kg = qkv + base + (size_t)256 * 4096;
  const unsigned short* vg = qkv + base + (size_t)512 * 4096;

  // --- stage Q,K as [h][w] (b128 rows), V transposed as Vt[w][g]
  {
    int h = t >> 2, w0 = (t & 3) * 16;
    const uint4* qp = (const uint4*)(qg + h * 64 + w0);
    const uint4* kp = (const uint4*)(kg + h * 64 + w0);
    uint4 q0 = qp[0], q1 = qp[1];
    uint4 k0 = kp[0], k1 = kp[1];
    *(uint4*)&Qs[h * 72 + w0]     = q0;
    *(uint4*)&Qs[h * 72 + w0 + 8] = q1;
    *(uint4*)&Ks[h * 72 + w0]     = k0;
    *(uint4*)&Ks[h * 72 + w0 + 8] = k1;

    int w = t & 63, gb = (t >> 6) * 16;
    unsigned short vv[16];
#pragma unroll
    for (int j = 0; j < 16; ++j) vv[j] = vg[(size_t)(gb + j) * 64 + w];
    *(uint4*)&Vt[w * 72 + gb]     = ((uint4*)vv)[0];
    *(uint4*)&Vt[w * 72 + gb + 8] = ((uint4*)vv)[1];
  }
  __syncthreads();

  int lane = t & 63, wave = t >> 6;
  int rt = lane & 15, quad = lane >> 4;
  int wm = wave >> 1, wn = wave & 1;

  // --- S = Q K^T via MFMA: 2x2 tiles of 16x16 per wave, K=64 (2 steps)
  f32x4 accs[2][2];
#pragma unroll
  for (int i = 0; i < 2; ++i)
#pragma unroll
    for (int j = 0; j < 2; ++j) accs[i][j] = (f32x4){0.f, 0.f, 0.f, 0.f};
#pragma unroll
  for (int ks = 0; ks < 2; ++ks) {
    int kk = ks * 32 + quad * 8;
    bf16x8 a0 = *(const bf16x8*)&Qs[(wm * 32 + rt) * 72 + kk];
    bf16x8 a1 = *(const bf16x8*)&Qs[(wm * 32 + 16 + rt) * 72 + kk];
    bf16x8 b0 = *(const bf16x8*)&Ks[(wn * 32 + rt) * 72 + kk];
    bf16x8 b1 = *(const bf16x8*)&Ks[(wn * 32 + 16 + rt) * 72 + kk];
    accs[0][0] = __builtin_amdgcn_mfma_f32_16x16x32_bf16(a0, b0, accs[0][0], 0, 0, 0);
    accs[0][1] = __builtin_amdgcn_mfma_f32_16x16x32_bf16(a0, b1, accs[0][1], 0, 0, 0);
    accs[1][0] = __builtin_amdgcn_mfma_f32_16x16x32_bf16(a1, b0, accs[1][0], 0, 0, 0);
    accs[1][1] = __builtin_amdgcn_mfma_f32_16x16x32_bf16(a1, b1, accs[1][1], 0, 0, 0);
  }
  __syncthreads();   // protect Qs/Ks before Sf/Ps overlay writes

  // write S (scaled) to Sf stride 65 (C/D: row=quad*4+reg, col=lane&15)
#pragma unroll
  for (int tm = 0; tm < 2; ++tm)
#pragma unroll
    for (int tn = 0; tn < 2; ++tn)
#pragma unroll
      for (int r = 0; r < 4; ++r)
        Sf[(wm * 32 + tm * 16 + quad * 4 + r) * 65 + wn * 32 + tn * 16 + rt] =
            accs[tm][tn][r] * INV_SQRT32;
  __syncthreads();

  // --- softmax over g: 4 threads/row, 16 elems each (held in regs)
  int hr = t & 63, qt = t >> 6;
  float s[16];
#pragma unroll
  for (int e = 0; e < 16; ++e) s[e] = Sf[hr * 65 + qt * 16 + e];
  float m = s[0];
#pragma unroll
  for (int e = 1; e < 16; ++e) m = fmaxf(m, s[e]);
  red[qt * 64 + hr] = m;
  __syncthreads();
  if (t < 64)
    rowmax[t] = fmaxf(fmaxf(red[t], red[64 + t]), fmaxf(red[128 + t], red[192 + t]));
  __syncthreads();
  float mr = rowmax[hr];
  float ssum = 0.f;
  unsigned short pv[16];
#pragma unroll
  for (int e = 0; e < 16; ++e) {
    float p = exp2f((s[e] - mr) * LOG2E);
    ssum += p;
    pv[e] = f2bf(p);
  }
  *(uint4*)&Ps[hr * 72 + qt * 16]     = ((uint4*)pv)[0];
  *(uint4*)&Ps[hr * 72 + qt * 16 + 8] = ((uint4*)pv)[1];
  red[qt * 64 + hr] = ssum;
  __syncthreads();
  if (t < 64) rowinv[t] = 1.f / (red[t] + red[64 + t] + red[128 + t] + red[192 + t]);
  __syncthreads();

  // --- O = P V via MFMA: A=Ps[h][g], B=Vt[w][g], contract g
  f32x4 acco[2][2];
#pragma unroll
  for (int i = 0; i < 2; ++i)
#pragma unroll
    for (int j = 0; j < 2; ++j) acco[i][j] = (f32x4){0.f, 0.f, 0.f, 0.f};
#pragma unroll
  for (int ks = 0; ks < 2; ++ks) {
    int kk = ks * 32 + quad * 8;
    bf16x8 a0 = *(const bf16x8*)&Ps[(wm * 32 + rt) * 72 + kk];
    bf16x8 a1 = *(const bf16x8*)&Ps[(wm * 32 + 16 + rt) * 72 + kk];
    bf16x8 b0 = *(const bf16x8*)&Vt[(wn * 32 + rt) * 72 + kk];
    bf16x8 b1 = *(const bf16x8*)&Vt[(wn * 32 + 16 + rt) * 72 + kk];
    acco[0][0] = __builtin_amdgcn_mfma_f32_16x16x32_bf16(a0, b0, acco[0][0], 0, 0, 0);
    acco[0][1] = __builtin_amdgcn_mfma_f32_16x16x32_bf16(a0, b1, acco[0][1], 0, 0, 0);
    acco[1][0] = __builtin_amdgcn_mfma_f32_16x16x32_bf16(a1, b0, acco[1][0], 0, 0, 0);
    acco[1][1] = __builtin_amdgcn_mfma_f32_16x16x32_bf16(a1, b1, acco[1][1], 0, 0, 0);
  }

  float* op = out + ((size_t)(b * 256 + o)) * 4096;
#pragma unroll
  for (int tm = 0; tm < 2; ++tm) {
#pragma unroll
    for (int r = 0; r < 4; ++r) {
      int h = wm * 32 + tm * 16 + quad * 4 + r;
      float inv = rowinv[h];
#pragma unroll
      for (int tn = 0; tn < 2; ++tn) {
        int w = wn * 32 + tn * 16 + rt;
        op[h * 64 + w] = acco[tm][tn][r] * inv;
      }
    }
  }
}

extern "C" void kernel_launch(void* const* d_in, const int* in_sizes, int n_in,
                              void* d_out, int out_size, void* d_ws, size_t ws_size,
                              hipStream_t stream) {
  const float* x  = (const float*)d_in[0];
  const float* wq = (const float*)d_in[1];
  const float* bq = (const float*)d_in[2];
  const float* wk = (const float*)d_in[3];
  const float* bk = (const float*)d_in[4];
  const float* wv = (const float*)d_in[5];
  const float* bv = (const float*)d_in[6];
  float* out = (float*)d_out;

  // workspace layout (bytes): Wcat bf16 393216 | bias fp32 3072 | Xt bf16 33554432 | qkv bf16 100663296
  char* ws = (char*)d_ws;
  unsigned short* Wcat  = (unsigned short*)ws;
  float*          biasc = (float*)(ws + 393216);
  unsigned short* Xt    = (unsigned short*)(ws + 396288);
  unsigned short* qkv   = (unsigned short*)(ws + 396288 + 33554432);

  hipLaunchKernelGGL(convert_w, dim3(192), dim3(256), 0, stream,
                     wq, bq, wk, bk, wv, bv, Wcat, biasc);
  hipLaunchKernelGGL(transpose_x, dim3(64, 4, 16), dim3(256), 0, stream, x, Xt);
  hipLaunchKernelGGL(gemm_qkv, dim3(3072), dim3(256), 0, stream, Wcat, biasc, Xt, qkv);
  hipLaunchKernelGGL(attn, dim3(4096), dim3(256), 0, stream, qkv, out);
}